// Round 1
// baseline (840.244 us; speedup 1.0000x reference)
//
#include <hip/hip_runtime.h>

#define B_ 32
#define C_ 384
#define N_ 4096
#define M_ 64
#define R_ 16

// ---------------- Kernel 1: V = Vw*x + Vb ; L = U*V ; S = softmax_M(L) -------
// One thread per pixel (b,n). x reads coalesced along n. Also zero-inits T.
__global__ __launch_bounds__(256) void k_proj_softmax(
    const float* __restrict__ x, const float* __restrict__ Vw,
    const float* __restrict__ Vb, const float* __restrict__ U,
    float* __restrict__ S, float* __restrict__ T)
{
    __shared__ float sVwT[C_][R_];   // transposed: [c][r], 24 KB
    __shared__ float sU[M_][R_];     // 4 KB
    __shared__ float sVb[R_];

    const int tid = threadIdx.x;

    // zero T (kernel 2 accumulates with atomics); grid covers exactly B*C*M
    {
        int gid = blockIdx.x * 256 + tid;
        for (int i = gid; i < B_ * C_ * M_; i += 512 * 256) T[i] = 0.0f;
    }

    for (int i = tid; i < R_ * C_; i += 256) {
        int r = i / C_, c = i - r * C_;
        sVwT[c][r] = Vw[i];
    }
    for (int i = tid; i < M_ * R_; i += 256) sU[i >> 4][i & 15] = U[i];
    if (tid < R_) sVb[tid] = Vb[tid];
    __syncthreads();

    const int b = blockIdx.x >> 4;                 // N/256 = 16 blocks per batch
    const int n = ((blockIdx.x & 15) << 8) | tid;

    const float* xp = x + (size_t)b * C_ * N_ + n;

    float V[R_];
    #pragma unroll
    for (int r = 0; r < R_; ++r) V[r] = sVb[r];

    #pragma unroll 8
    for (int c = 0; c < C_; ++c) {
        float xv = xp[(size_t)c * N_];             // coalesced: 64 lanes x 4B
        const float4* w4 = (const float4*)(&sVwT[c][0]);  // wave-uniform broadcast
        #pragma unroll
        for (int q = 0; q < 4; ++q) {
            float4 w = w4[q];
            V[4*q+0] = fmaf(w.x, xv, V[4*q+0]);
            V[4*q+1] = fmaf(w.y, xv, V[4*q+1]);
            V[4*q+2] = fmaf(w.z, xv, V[4*q+2]);
            V[4*q+3] = fmaf(w.w, xv, V[4*q+3]);
        }
    }

    float L[M_];
    float mx = -3.0e38f;
    #pragma unroll
    for (int m = 0; m < M_; ++m) {
        const float4* u4 = (const float4*)(&sU[m][0]);
        float l0 = 0.f, l1 = 0.f, l2 = 0.f, l3 = 0.f;
        #pragma unroll
        for (int q = 0; q < 4; ++q) {
            float4 u = u4[q];
            l0 = fmaf(u.x, V[4*q+0], l0);
            l1 = fmaf(u.y, V[4*q+1], l1);
            l2 = fmaf(u.z, V[4*q+2], l2);
            l3 = fmaf(u.w, V[4*q+3], l3);
        }
        float l = (l0 + l1) + (l2 + l3);
        L[m] = l;
        mx = fmaxf(mx, l);
    }
    float sum = 0.0f;
    #pragma unroll
    for (int m = 0; m < M_; ++m) {
        float e = __expf(L[m] - mx);
        L[m] = e;
        sum += e;
    }
    const float inv = 1.0f / sum;
    float* Sp = S + (size_t)b * M_ * N_ + n;
    #pragma unroll
    for (int m = 0; m < M_; ++m) Sp[(size_t)m * N_] = L[m] * inv;   // coalesced
}

// ---------------- Kernel 2: T[b,c,m] = sum_n x[b,c,n] * S[b,m,n] -------------
// Tiled fp32 "GEMM": block = (32 c) x (64 m), k-sliced by 1024 with atomicAdd.
#define CT 32
#define KC 64
#define KSLICE 1024

__global__ __launch_bounds__(256) void k_pool(
    const float* __restrict__ x, const float* __restrict__ S,
    float* __restrict__ T)
{
    __shared__ float xs[CT][KC + 4];  // +4 pad keeps 16B alignment, 2-way banks (free)
    __shared__ float ss[M_][KC + 4];

    const int tid = threadIdx.x;
    const int b  = blockIdx.y;
    const int cb = blockIdx.x % (C_ / CT);   // 12 c-tiles
    const int ks = blockIdx.x / (C_ / CT);   // 4 k-slices

    const int tx = tid & 15;   // m-group: 4 m's each
    const int ty = tid >> 4;   // c-group: 2 c's each

    const float* xb = x + (size_t)b * C_ * N_ + (size_t)(cb * CT) * N_;
    const float* sb = S + (size_t)b * M_ * N_;

    float acc[2][4] = {{0,0,0,0},{0,0,0,0}};

    const int k_end = ks * KSLICE + KSLICE;
    for (int k0 = ks * KSLICE; k0 < k_end; k0 += KC) {
        #pragma unroll
        for (int l = 0; l < 2; ++l) {
            int idx = tid + l * 256;
            int row = idx >> 4, col = (idx & 15) << 2;
            *(float4*)(&xs[row][col]) =
                *(const float4*)(xb + (size_t)row * N_ + k0 + col);
        }
        #pragma unroll
        for (int l = 0; l < 4; ++l) {
            int idx = tid + l * 256;
            int row = idx >> 4, col = (idx & 15) << 2;
            *(float4*)(&ss[row][col]) =
                *(const float4*)(sb + (size_t)row * N_ + k0 + col);
        }
        __syncthreads();

        #pragma unroll
        for (int kk = 0; kk < KC; kk += 4) {
            float4 xa = *(const float4*)(&xs[ty * 2 + 0][kk]);
            float4 xc = *(const float4*)(&xs[ty * 2 + 1][kk]);
            #pragma unroll
            for (int j = 0; j < 4; ++j) {
                float4 sv = *(const float4*)(&ss[tx * 4 + j][kk]);
                acc[0][j] = fmaf(xa.x, sv.x, acc[0][j]);
                acc[0][j] = fmaf(xa.y, sv.y, acc[0][j]);
                acc[0][j] = fmaf(xa.z, sv.z, acc[0][j]);
                acc[0][j] = fmaf(xa.w, sv.w, acc[0][j]);
                acc[1][j] = fmaf(xc.x, sv.x, acc[1][j]);
                acc[1][j] = fmaf(xc.y, sv.y, acc[1][j]);
                acc[1][j] = fmaf(xc.z, sv.z, acc[1][j]);
                acc[1][j] = fmaf(xc.w, sv.w, acc[1][j]);
            }
        }
        __syncthreads();
    }

    float* Tb = T + (size_t)b * C_ * M_ + (size_t)(cb * CT) * M_;
    #pragma unroll
    for (int i = 0; i < 2; ++i)
        #pragma unroll
        for (int j = 0; j < 4; ++j)
            atomicAdd(&Tb[(size_t)(ty * 2 + i) * M_ + tx * 4 + j], acc[i][j]);
}

extern "C" void kernel_launch(void* const* d_in, const int* in_sizes, int n_in,
                              void* d_out, int out_size, void* d_ws, size_t ws_size,
                              hipStream_t stream) {
    const float* x  = (const float*)d_in[0];
    const float* Vw = (const float*)d_in[1];
    const float* Vb = (const float*)d_in[2];
    const float* U  = (const float*)d_in[3];
    float* T = (float*)d_out;                              // [B,C,M] first
    float* S = (float*)d_out + (size_t)B_ * C_ * M_;       // then [B,M,N]

    k_proj_softmax<<<dim3(B_ * (N_ / 256)), dim3(256), 0, stream>>>(x, Vw, Vb, U, S, T);
    k_pool<<<dim3((C_ / CT) * (N_ / KSLICE), B_), dim3(256), 0, stream>>>(x, S, T);
}

// Round 2
// 369.083 us; speedup vs baseline: 2.2766x; 2.2766x over previous
//
#include <hip/hip_runtime.h>
#include <hip/hip_bf16.h>

#define B_ 32
#define C_ 384
#define N_ 4096
#define M_ 64
#define R_ 16

typedef __attribute__((ext_vector_type(8))) short short8;
typedef __attribute__((ext_vector_type(4))) float f32x4;
typedef __attribute__((ext_vector_type(4))) int i32x4;

static __device__ __forceinline__ unsigned short f2bf(float f) {
    union { float f; unsigned u; } v; v.f = f;
    unsigned r = v.u + 0x7fffu + ((v.u >> 16) & 1u);   // RNE
    return (unsigned short)(r >> 16);
}

// =====================================================================
// Kernel 1: W2 = U*Vw (per-block prologue, bf16); L = W2*x + b2 via MFMA;
//           softmax over m; write S fp32.
// Block: 256 thr (4 waves). Each block: one (b, 128-n tile). Grid 32*32=1024.
// LDS: w2s[64][392]bf16 (50176) + scratch(28928: VwU phase-A / xts[128][72] phase-B)
//      + b2s/vbs. Total ~79.4 KB -> 2 blocks/CU.
// Row strides 392 bf16 (784B) and 72 bf16 (144B): (bytes/16) odd -> b128 bank-balanced.
// =====================================================================
__global__ __launch_bounds__(256, 2) void k_logits_softmax(
    const float* __restrict__ x, const float* __restrict__ Vw,
    const float* __restrict__ Vb, const float* __restrict__ U,
    float* __restrict__ S)
{
    __shared__ unsigned short w2s[64][392];
    __shared__ __align__(16) char scratch[28928];
    __shared__ float b2s[64];
    __shared__ float vbs[16];

    float* vws = (float*)scratch;                 // [16][384] fp32 (phase A)
    float* us  = (float*)(scratch + 24576);       // [64][17]  fp32 (phase A)
    unsigned short (*xts)[72] = (unsigned short (*)[72])scratch;  // phase B

    const int t = threadIdx.x;

    // ---------------- Phase A: W2 = U*Vw, b2 = U*Vb ----------------
    {
        const float4* vw4 = (const float4*)Vw;
        #pragma unroll
        for (int i = 0; i < 6; ++i)
            ((float4*)vws)[t + i * 256] = vw4[t + i * 256];
        // U: 1024 floats, pad rows to 17
        float4 uv = ((const float4*)U)[t];
        const int um = t >> 2, ur0 = (t & 3) * 4;
        us[um * 17 + ur0 + 0] = uv.x;
        us[um * 17 + ur0 + 1] = uv.y;
        us[um * 17 + ur0 + 2] = uv.z;
        us[um * 17 + ur0 + 3] = uv.w;
        if (t < 16) vbs[t] = Vb[t];
    }
    __syncthreads();
    {
        const int m  = t >> 2;
        const int cg = t & 3;
        float u[R_];
        #pragma unroll
        for (int r = 0; r < R_; ++r) u[r] = us[m * 17 + r];
        if (cg == 0) {
            float a = 0.f;
            #pragma unroll
            for (int r = 0; r < R_; ++r) a = fmaf(u[r], vbs[r], a);
            b2s[m] = a;
        }
        #pragma unroll 4
        for (int j = 0; j < 48; ++j) {
            const int c = cg * 2 + j * 8;            // even
            float a0 = 0.f, a1 = 0.f;
            #pragma unroll
            for (int r = 0; r < R_; ++r) {
                float2 vv = *(const float2*)(vws + r * C_ + c);
                a0 = fmaf(u[r], vv.x, a0);
                a1 = fmaf(u[r], vv.y, a1);
            }
            unsigned pk = (unsigned)f2bf(a0) | ((unsigned)f2bf(a1) << 16);
            *(unsigned*)&w2s[m][c] = pk;
        }
    }
    __syncthreads();   // w2s ready; scratch now reusable as xts

    // ---------------- Phase B: MFMA K-loop ----------------
    const int b    = blockIdx.x >> 5;
    const int n0   = (blockIdx.x & 31) * 128;
    const int lane = t & 63, q = lane >> 4, col = lane & 15;
    const int w    = t >> 6;                       // wave id (also staging c-group)

    f32x4 acc[4][2];
    #pragma unroll
    for (int mt = 0; mt < 4; ++mt)
        #pragma unroll
        for (int nt = 0; nt < 2; ++nt)
            acc[mt][nt] = (f32x4){0.f, 0.f, 0.f, 0.f};

    const float* xbase = x + (size_t)(b * C_) * N_ + n0 + 2 * lane;

    for (int kc = 0; kc < 12; ++kc) {              // K = 384 in chunks of 32
        // stage x[kc*32..+32][n0..n0+128] -> xts[n][c] bf16 (transposed)
        unsigned wA[4], wB[4];
        const float* xp = xbase + (size_t)(kc * 32 + w * 8) * N_;
        #pragma unroll
        for (int i = 0; i < 8; ++i) {
            float2 v = *(const float2*)(xp + (size_t)i * N_);
            unsigned ba = f2bf(v.x), bb = f2bf(v.y);
            if ((i & 1) == 0) { wA[i >> 1] = ba;        wB[i >> 1] = bb; }
            else              { wA[i >> 1] |= ba << 16; wB[i >> 1] |= bb << 16; }
        }
        __syncthreads();   // previous iter's LDS reads (or phase A) done
        {
            const int nl = 2 * lane;
            i32x4 pa = {(int)wA[0], (int)wA[1], (int)wA[2], (int)wA[3]};
            i32x4 pb = {(int)wB[0], (int)wB[1], (int)wB[2], (int)wB[3]};
            *(i32x4*)&xts[nl][w * 8]     = pa;
            *(i32x4*)&xts[nl + 1][w * 8] = pb;
        }
        __syncthreads();

        short8 af[4], bfr[2];
        #pragma unroll
        for (int mt = 0; mt < 4; ++mt)
            af[mt] = *(const short8*)&w2s[mt * 16 + col][kc * 32 + q * 8];
        #pragma unroll
        for (int nt = 0; nt < 2; ++nt)
            bfr[nt] = *(const short8*)&xts[w * 32 + nt * 16 + col][q * 8];
        #pragma unroll
        for (int mt = 0; mt < 4; ++mt)
            #pragma unroll
            for (int nt = 0; nt < 2; ++nt)
                acc[mt][nt] = __builtin_amdgcn_mfma_f32_16x16x32_bf16(
                    af[mt], bfr[nt], acc[mt][nt], 0, 0, 0);
    }

    // ---------------- Epilogue: bias + softmax over m, write S ----------------
    float bias[4][4];
    #pragma unroll
    for (int mt = 0; mt < 4; ++mt)
        #pragma unroll
        for (int r = 0; r < 4; ++r)
            bias[mt][r] = b2s[mt * 16 + q * 4 + r];

    float* Sb = S + (size_t)(b * M_) * N_ + n0 + w * 32 + col;
    #pragma unroll
    for (int nt = 0; nt < 2; ++nt) {
        float mx = -3.4e38f;
        #pragma unroll
        for (int mt = 0; mt < 4; ++mt)
            #pragma unroll
            for (int r = 0; r < 4; ++r) {
                float v = acc[mt][nt][r] + bias[mt][r];
                acc[mt][nt][r] = v;
                mx = fmaxf(mx, v);
            }
        mx = fmaxf(mx, __shfl_xor(mx, 16, 64));
        mx = fmaxf(mx, __shfl_xor(mx, 32, 64));
        float sm = 0.f;
        #pragma unroll
        for (int mt = 0; mt < 4; ++mt)
            #pragma unroll
            for (int r = 0; r < 4; ++r) {
                float e = __expf(acc[mt][nt][r] - mx);
                acc[mt][nt][r] = e;
                sm += e;
            }
        sm += __shfl_xor(sm, 16, 64);
        sm += __shfl_xor(sm, 32, 64);
        const float inv = 1.0f / sm;
        #pragma unroll
        for (int mt = 0; mt < 4; ++mt)
            #pragma unroll
            for (int r = 0; r < 4; ++r)
                Sb[(size_t)(mt * 16 + q * 4 + r) * N_ + nt * 16] = acc[mt][nt][r] * inv;
    }
}

// =====================================================================
// Kernel 2: T[b,c,m] = sum_n x[b,c,n]*S[b,m,n]  via bf16 MFMA.
// Grid (6 c-tiles, 32 b, 4 n-quarters), 256 thr. atomicAdd fp32 epilogue
// (T zeroed by hipMemsetAsync). LDS 2x 64x72 bf16 tiles (18.4 KB).
// =====================================================================
__global__ __launch_bounds__(256, 3) void k_pool2(
    const float* __restrict__ x, const float* __restrict__ S,
    float* __restrict__ T)
{
    __shared__ unsigned short xls[64][72];
    __shared__ unsigned short sls[64][72];

    const int t  = threadIdx.x;
    const int ct = blockIdx.x;          // 0..5
    const int b  = blockIdx.y;          // 0..31
    const int nq = blockIdx.z;          // 0..3
    const int c0 = ct * 64;

    const int rl = t >> 2;              // staging row 0..63
    const int ns = (t & 3) * 16;        // n-seg within 64

    const float* xp = x + (size_t)(b * C_ + c0 + rl) * N_ + nq * 1024 + ns;
    const float* sp = S + (size_t)(b * M_ + rl) * N_ + nq * 1024 + ns;

    const int lane = t & 63, q = lane >> 4, col = lane & 15;
    const int w    = t >> 6;

    f32x4 acc[4];
    #pragma unroll
    for (int mt = 0; mt < 4; ++mt) acc[mt] = (f32x4){0.f, 0.f, 0.f, 0.f};

    for (int kc = 0; kc < 16; ++kc) {   // 1024 n in chunks of 64
        float4 xv[4], sv[4];
        #pragma unroll
        for (int u = 0; u < 4; ++u) {
            xv[u] = *(const float4*)(xp + kc * 64 + u * 4);
            sv[u] = *(const float4*)(sp + kc * 64 + u * 4);
        }
        unsigned wx[8], ws[8];
        #pragma unroll
        for (int u = 0; u < 4; ++u) {
            wx[u*2]   = (unsigned)f2bf(xv[u].x) | ((unsigned)f2bf(xv[u].y) << 16);
            wx[u*2+1] = (unsigned)f2bf(xv[u].z) | ((unsigned)f2bf(xv[u].w) << 16);
            ws[u*2]   = (unsigned)f2bf(sv[u].x) | ((unsigned)f2bf(sv[u].y) << 16);
            ws[u*2+1] = (unsigned)f2bf(sv[u].z) | ((unsigned)f2bf(sv[u].w) << 16);
        }
        __syncthreads();
        {
            i32x4 p0 = {(int)wx[0], (int)wx[1], (int)wx[2], (int)wx[3]};
            i32x4 p1 = {(int)wx[4], (int)wx[5], (int)wx[6], (int)wx[7]};
            i32x4 p2 = {(int)ws[0], (int)ws[1], (int)ws[2], (int)ws[3]};
            i32x4 p3 = {(int)ws[4], (int)ws[5], (int)ws[6], (int)ws[7]};
            *(i32x4*)&xls[rl][ns]     = p0;
            *(i32x4*)&xls[rl][ns + 8] = p1;
            *(i32x4*)&sls[rl][ns]     = p2;
            *(i32x4*)&sls[rl][ns + 8] = p3;
        }
        __syncthreads();

        #pragma unroll
        for (int ks = 0; ks < 2; ++ks) {
            short8 af = *(const short8*)&xls[w * 16 + col][ks * 32 + q * 8];
            #pragma unroll
            for (int mt = 0; mt < 4; ++mt) {
                short8 bfr = *(const short8*)&sls[mt * 16 + col][ks * 32 + q * 8];
                acc[mt] = __builtin_amdgcn_mfma_f32_16x16x32_bf16(af, bfr, acc[mt], 0, 0, 0);
            }
        }
    }

    float* Tb = T + (size_t)b * C_ * M_;
    #pragma unroll
    for (int mt = 0; mt < 4; ++mt)
        #pragma unroll
        for (int r = 0; r < 4; ++r)
            atomicAdd(&Tb[(size_t)(c0 + w * 16 + q * 4 + r) * M_ + mt * 16 + col],
                      acc[mt][r]);
}

extern "C" void kernel_launch(void* const* d_in, const int* in_sizes, int n_in,
                              void* d_out, int out_size, void* d_ws, size_t ws_size,
                              hipStream_t stream) {
    const float* x  = (const float*)d_in[0];
    const float* Vw = (const float*)d_in[1];
    const float* Vb = (const float*)d_in[2];
    const float* U  = (const float*)d_in[3];
    float* T = (float*)d_out;                               // [B,C,M]
    float* S = (float*)d_out + (size_t)B_ * C_ * M_;        // [B,M,N]

    hipMemsetAsync(T, 0, (size_t)B_ * C_ * M_ * sizeof(float), stream);
    k_logits_softmax<<<dim3(32 * 32), dim3(256), 0, stream>>>(x, Vw, Vb, U, S);
    k_pool2<<<dim3(6, 32, 4), dim3(256), 0, stream>>>(x, S, T);
}

// Round 3
// 337.471 us; speedup vs baseline: 2.4898x; 1.0937x over previous
//
#include <hip/hip_runtime.h>
#include <hip/hip_bf16.h>

#define B_ 32
#define C_ 384
#define N_ 4096
#define M_ 64
#define R_ 16

typedef __attribute__((ext_vector_type(8))) short short8;
typedef __attribute__((ext_vector_type(4))) float f32x4;
typedef __attribute__((ext_vector_type(4))) int i32x4;

static __device__ __forceinline__ unsigned short f2bf(float f) {
    union { float f; unsigned u; } v; v.f = f;
    unsigned r = v.u + 0x7fffu + ((v.u >> 16) & 1u);   // RNE
    return (unsigned short)(r >> 16);
}

// =====================================================================
// Kernel 0: W2 = U*Vw (bf16, flat [64][384]) and b2 = U*Vb (f32[64]) -> d_ws.
// 8 blocks x 256 thr; each block does 8 m-rows. ~1-2 us.
// =====================================================================
__global__ __launch_bounds__(256) void k_w2(
    const float* __restrict__ Vw, const float* __restrict__ Vb,
    const float* __restrict__ U, unsigned short* __restrict__ W2,
    float* __restrict__ b2)
{
    __shared__ float vws[16 * 384];   // 24 KB
    __shared__ float vbs[16];
    const int t = threadIdx.x;

    #pragma unroll
    for (int j = 0; j < 6; ++j)
        ((float4*)vws)[t + j * 256] = ((const float4*)Vw)[t + j * 256];
    if (t < 16) vbs[t] = Vb[t];
    __syncthreads();

    const int m  = blockIdx.x * 8 + (t >> 5);
    const int cg = t & 31;
    float u[R_];
    #pragma unroll
    for (int r = 0; r < R_; ++r) u[r] = U[m * R_ + r];
    if (cg == 0) {
        float a = 0.f;
        #pragma unroll
        for (int r = 0; r < R_; ++r) a = fmaf(u[r], vbs[r], a);
        b2[m] = a;
    }
    #pragma unroll
    for (int j = 0; j < 6; ++j) {
        const int c = cg * 2 + j * 64;
        float a0 = 0.f, a1 = 0.f;
        #pragma unroll
        for (int r = 0; r < R_; ++r) {
            float2 vv = *(const float2*)(vws + r * C_ + c);
            a0 = fmaf(u[r], vv.x, a0);
            a1 = fmaf(u[r], vv.y, a1);
        }
        unsigned pk = (unsigned)f2bf(a0) | ((unsigned)f2bf(a1) << 16);
        *(unsigned*)&W2[m * C_ + c] = pk;
    }
}

// =====================================================================
// Kernel 1: L = W2*x + b2 via MFMA; softmax over m; write S fp32.
// Block: 256 thr. Each block: one (b, 128-n tile). Grid 32*32=1024.
// LDS: w2s[64][392]bf16 (50176) + xts[128][72] (18432) + b2s -> ~69 KB, 2/CU.
// =====================================================================
__global__ __launch_bounds__(256, 2) void k_logits_softmax(
    const float* __restrict__ x, const unsigned short* __restrict__ W2,
    const float* __restrict__ b2, float* __restrict__ S)
{
    __shared__ unsigned short w2s[64][392];
    __shared__ unsigned short xts[128][72];
    __shared__ float b2s[64];

    const int t = threadIdx.x;

    // stage W2 (49152 B = 3072 x 16B) into padded LDS; b2
    #pragma unroll
    for (int j = 0; j < 12; ++j) {
        int idx = t + j * 256;
        int m = idx / 48, c8 = idx % 48;
        *(i32x4*)&w2s[m][c8 * 8] = ((const i32x4*)W2)[idx];
    }
    if (t < 64) b2s[t] = b2[t];

    const int b    = blockIdx.x >> 5;
    const int n0   = (blockIdx.x & 31) * 128;
    const int lane = t & 63, q = lane >> 4, col = lane & 15;
    const int w    = t >> 6;

    f32x4 acc[4][2];
    #pragma unroll
    for (int mt = 0; mt < 4; ++mt)
        #pragma unroll
        for (int nt = 0; nt < 2; ++nt)
            acc[mt][nt] = (f32x4){0.f, 0.f, 0.f, 0.f};

    const float* xbase = x + (size_t)(b * C_) * N_ + n0 + 2 * lane;

    for (int kc = 0; kc < 12; ++kc) {              // K = 384 in chunks of 32
        unsigned wA[4], wB[4];
        const float* xp = xbase + (size_t)(kc * 32 + w * 8) * N_;
        #pragma unroll
        for (int i = 0; i < 8; ++i) {
            float2 v = *(const float2*)(xp + (size_t)i * N_);
            unsigned ba = f2bf(v.x), bb = f2bf(v.y);
            if ((i & 1) == 0) { wA[i >> 1] = ba;        wB[i >> 1] = bb; }
            else              { wA[i >> 1] |= ba << 16; wB[i >> 1] |= bb << 16; }
        }
        __syncthreads();   // prev iter's LDS reads done (also covers w2s staging)
        {
            const int nl = 2 * lane;
            i32x4 pa = {(int)wA[0], (int)wA[1], (int)wA[2], (int)wA[3]};
            i32x4 pb = {(int)wB[0], (int)wB[1], (int)wB[2], (int)wB[3]};
            *(i32x4*)&xts[nl][w * 8]     = pa;
            *(i32x4*)&xts[nl + 1][w * 8] = pb;
        }
        __syncthreads();

        short8 af[4], bfr[2];
        #pragma unroll
        for (int mt = 0; mt < 4; ++mt)
            af[mt] = *(const short8*)&w2s[mt * 16 + col][kc * 32 + q * 8];
        #pragma unroll
        for (int nt = 0; nt < 2; ++nt)
            bfr[nt] = *(const short8*)&xts[w * 32 + nt * 16 + col][q * 8];
        #pragma unroll
        for (int mt = 0; mt < 4; ++mt)
            #pragma unroll
            for (int nt = 0; nt < 2; ++nt)
                acc[mt][nt] = __builtin_amdgcn_mfma_f32_16x16x32_bf16(
                    af[mt], bfr[nt], acc[mt][nt], 0, 0, 0);
    }

    // bias + softmax over m, write S
    float bias[4][4];
    #pragma unroll
    for (int mt = 0; mt < 4; ++mt)
        #pragma unroll
        for (int r = 0; r < 4; ++r)
            bias[mt][r] = b2s[mt * 16 + q * 4 + r];

    float* Sb = S + (size_t)(b * M_) * N_ + n0 + w * 32 + col;
    #pragma unroll
    for (int nt = 0; nt < 2; ++nt) {
        float mx = -3.4e38f;
        #pragma unroll
        for (int mt = 0; mt < 4; ++mt)
            #pragma unroll
            for (int r = 0; r < 4; ++r) {
                float v = acc[mt][nt][r] + bias[mt][r];
                acc[mt][nt][r] = v;
                mx = fmaxf(mx, v);
            }
        mx = fmaxf(mx, __shfl_xor(mx, 16, 64));
        mx = fmaxf(mx, __shfl_xor(mx, 32, 64));
        float sm = 0.f;
        #pragma unroll
        for (int mt = 0; mt < 4; ++mt)
            #pragma unroll
            for (int r = 0; r < 4; ++r) {
                float e = __expf(acc[mt][nt][r] - mx);
                acc[mt][nt][r] = e;
                sm += e;
            }
        sm += __shfl_xor(sm, 16, 64);
        sm += __shfl_xor(sm, 32, 64);
        const float inv = 1.0f / sm;
        #pragma unroll
        for (int mt = 0; mt < 4; ++mt)
            #pragma unroll
            for (int r = 0; r < 4; ++r)
                Sb[(size_t)(mt * 16 + q * 4 + r) * N_ + nt * 16] = acc[mt][nt][r] * inv;
    }
}

// =====================================================================
// Kernel 2: T[b,c,m] = sum_n x[b,c,n]*S[b,m,n]  via bf16 MFMA.
// c-tile 128, n-range 512/block. Grid (3, 32, 8) = 768 blocks, 256 thr.
// LDS xls[128][72] + sls[64][72] = 27.9 KB -> 4 blocks/CU. atomicAdd epilogue.
// =====================================================================
__global__ __launch_bounds__(256, 4) void k_pool2(
    const float* __restrict__ x, const float* __restrict__ S,
    float* __restrict__ T)
{
    __shared__ unsigned short xls[128][72];
    __shared__ unsigned short sls[64][72];

    const int t  = threadIdx.x;
    const int ct = blockIdx.x;          // 0..2
    const int b  = blockIdx.y;          // 0..31
    const int nq = blockIdx.z;          // 0..7 (512 n each)
    const int c0 = ct * 128;

    const float* xb = x + (size_t)(b * C_ + c0) * N_ + nq * 512;
    const float* sb = S + (size_t)(b * M_) * N_ + nq * 512;

    const int lane = t & 63, q = lane >> 4, col = lane & 15;
    const int w    = t >> 6;

    f32x4 acc[2][4];
    #pragma unroll
    for (int i = 0; i < 2; ++i)
        #pragma unroll
        for (int mt = 0; mt < 4; ++mt) acc[i][mt] = (f32x4){0.f, 0.f, 0.f, 0.f};

    for (int kc = 0; kc < 8; ++kc) {   // 512 n in chunks of 64
        float4 xv[8], sv[4];
        #pragma unroll
        for (int j = 0; j < 8; ++j) {
            int idx = t + j * 256;
            int row = idx >> 4, cc = idx & 15;
            xv[j] = *(const float4*)(xb + (size_t)row * N_ + kc * 64 + cc * 4);
        }
        #pragma unroll
        for (int j = 0; j < 4; ++j) {
            int idx = t + j * 256;
            int row = idx >> 4, cc = idx & 15;
            sv[j] = *(const float4*)(sb + (size_t)row * N_ + kc * 64 + cc * 4);
        }
        __syncthreads();
        #pragma unroll
        for (int j = 0; j < 8; ++j) {
            int idx = t + j * 256;
            int row = idx >> 4, cc = idx & 15;
            int2 p;
            p.x = (int)((unsigned)f2bf(xv[j].x) | ((unsigned)f2bf(xv[j].y) << 16));
            p.y = (int)((unsigned)f2bf(xv[j].z) | ((unsigned)f2bf(xv[j].w) << 16));
            *(int2*)&xls[row][cc * 4] = p;
        }
        #pragma unroll
        for (int j = 0; j < 4; ++j) {
            int idx = t + j * 256;
            int row = idx >> 4, cc = idx & 15;
            int2 p;
            p.x = (int)((unsigned)f2bf(sv[j].x) | ((unsigned)f2bf(sv[j].y) << 16));
            p.y = (int)((unsigned)f2bf(sv[j].z) | ((unsigned)f2bf(sv[j].w) << 16));
            *(int2*)&sls[row][cc * 4] = p;
        }
        __syncthreads();

        #pragma unroll
        for (int ks = 0; ks < 2; ++ks) {
            short8 af[2];
            #pragma unroll
            for (int i = 0; i < 2; ++i)
                af[i] = *(const short8*)&xls[w * 32 + i * 16 + col][ks * 32 + q * 8];
            #pragma unroll
            for (int mt = 0; mt < 4; ++mt) {
                short8 bfr = *(const short8*)&sls[mt * 16 + col][ks * 32 + q * 8];
                #pragma unroll
                for (int i = 0; i < 2; ++i)
                    acc[i][mt] = __builtin_amdgcn_mfma_f32_16x16x32_bf16(
                        af[i], bfr, acc[i][mt], 0, 0, 0);
            }
        }
        __syncthreads();
    }

    float* Tb = T + (size_t)b * C_ * M_ + (size_t)c0 * M_;
    #pragma unroll
    for (int i = 0; i < 2; ++i)
        #pragma unroll
        for (int mt = 0; mt < 4; ++mt)
            #pragma unroll
            for (int r = 0; r < 4; ++r)
                atomicAdd(&Tb[(size_t)(w * 32 + i * 16 + q * 4 + r) * M_ + mt * 16 + col],
                          acc[i][mt][r]);
}

extern "C" void kernel_launch(void* const* d_in, const int* in_sizes, int n_in,
                              void* d_out, int out_size, void* d_ws, size_t ws_size,
                              hipStream_t stream) {
    const float* x  = (const float*)d_in[0];
    const float* Vw = (const float*)d_in[1];
    const float* Vb = (const float*)d_in[2];
    const float* U  = (const float*)d_in[3];
    float* T = (float*)d_out;                               // [B,C,M]
    float* S = (float*)d_out + (size_t)B_ * C_ * M_;        // [B,M,N]

    unsigned short* W2 = (unsigned short*)d_ws;             // [64][384] bf16
    float* b2 = (float*)((char*)d_ws + 64 * 384 * 2);       // [64] f32

    hipMemsetAsync(T, 0, (size_t)B_ * C_ * M_ * sizeof(float), stream);
    k_w2<<<dim3(8), dim3(256), 0, stream>>>(Vw, Vb, U, W2, b2);
    k_logits_softmax<<<dim3(32 * 32), dim3(256), 0, stream>>>(x, W2, b2, S);
    k_pool2<<<dim3(3, 32, 8), dim3(256), 0, stream>>>(x, S, T);
}